// Round 3
// baseline (58.865 us; speedup 1.0000x reference)
//
#include <hip/hip_runtime.h>

#define MH 28
#define MW 28
#define CC 64
#define GG 4
#define NB 32
#define CSPLIT 4
#define CHP 16   // channels per split

// ws layout:
//   [0, 64)      : uint counters {mask_cnt, dil_cnt, arrivals}
//   [256, +3.2MB): partial logits, float [B*28][CSPLIT][224]

// ---------- Kernel A: pooled partial projection over a 16-channel slice ----------
// grid: B*MH*CSPLIT blocks (sp fastest), 256 threads
__global__ __launch_bounds__(256) void masker_pool(
    const float* __restrict__ x, const float* __restrict__ w,
    float* __restrict__ plog, unsigned int* __restrict__ cnts)
{
    int blk = blockIdx.x;
    int sp  = blk & 3;
    int bc  = blk >> 2;            // b*28 + ch
    int b   = bc / MH;
    int ch  = bc - b * MH;
    int t   = threadIdx.x;

    if (blk == 0 && t < 3) cnts[t] = 0u;   // zero counters for kernel B

    __shared__ float pooled[CHP][MW];
    __shared__ float wlds[8][CHP];

    // weight slice w[o][sp*16 + j]: 128 floats as 32 float4
    if (t < 32) {
        int o = t >> 2, q = t & 3;
        float4 v = *(const float4*)(w + o * CC + sp * CHP + q * 4);
        wlds[o][q * 4 + 0] = v.x; wlds[o][q * 4 + 1] = v.y;
        wlds[o][q * 4 + 2] = v.z; wlds[o][q * 4 + 3] = v.w;
    }

    // 448 cells: c(16) x cw(28); 4x4 pool each, float4 loads
    const float* xb = x + ((size_t)b * CC + sp * CHP) * (112 * 112)
                        + (size_t)(4 * ch) * 112;
    #pragma unroll
    for (int k = 0; k < 2; ++k) {
        int p = t + 256 * k;
        if (p < 448) {
            int c  = p / MW;
            int cw = p - c * MW;
            const float* base = xb + (size_t)c * (112 * 112) + 4 * cw;
            float s = 0.f;
            #pragma unroll
            for (int hh = 0; hh < 4; ++hh) {
                float4 v = *(const float4*)(base + hh * 112);
                s += v.x + v.y + v.z + v.w;
            }
            pooled[c][cw] = s * 0.0625f;
        }
    }
    __syncthreads();

    // partial projection: 8 outputs x 28 cols over 16 channels
    if (t < 8 * MW) {
        int o  = t / MW;
        int cw = t - o * MW;
        float acc = 0.f;
        #pragma unroll
        for (int c = 0; c < CHP; ++c)
            acc += pooled[c][cw] * wlds[o][c];
        plog[((size_t)bc * CSPLIT + sp) * 224 + t] = acc;
    }
}

// ---------- Kernel B: combine + decide(3 rows) + upsample + dilate + finalize ----
// grid: B*MH blocks, 256 threads
__global__ __launch_bounds__(256) void masker_fuse(
    const float* __restrict__ plog, const float* __restrict__ bias,
    const float* __restrict__ gum,
    float* __restrict__ out_mask, float* __restrict__ out_dil,
    unsigned int* __restrict__ cnts, float* __restrict__ out_scalars)
{
    int blk = blockIdx.x;
    int b   = blk / MH;
    int ch  = blk - b * MH;
    int t   = threadIdx.x;

    __shared__ float L[3][8][MW];     // logits rows ch-1..ch+1
    __shared__ float dec[3][GG][MW];  // decisions (0/1), 0 for invalid rows
    __shared__ float R[3][MW + 2];    // row-OR variants, zero-padded
    __shared__ unsigned int sm[4], sd[4];

    // sum 4 partials + bias for 3 rows x 224 outputs
    for (int idx = t; idx < 3 * 224; idx += 256) {
        int r = idx / 224, j = idx - r * 224;
        int row = ch - 1 + r;
        float acc = bias[j / MW];
        if (row >= 0 && row < MH) {
            const float* p = plog + (size_t)(b * MH + row) * CSPLIT * 224 + j;
            acc += p[0] + p[224] + p[448] + p[672];   // fixed order: deterministic
        }
        L[r][j / MW][j % MW] = acc;
    }
    __syncthreads();

    // gumbel decisions for 3 rows (T>0 scaling is argmax-invariant; ties -> idx 0)
    for (int idx = t; idx < 3 * GG * MW; idx += 256) {
        int r = idx / (GG * MW), rem = idx - r * (GG * MW);
        int g = rem / MW, cw = rem - g * MW;
        int row = ch - 1 + r;
        float d = 0.f;
        if (row >= 0 && row < MH) {
            float g0 = gum[((((size_t)b * 2 + 0) * GG + g) * MH + row) * MW + cw];
            float g1 = gum[((((size_t)b * 2 + 1) * GG + g) * MH + row) * MW + cw];
            d = (L[r][g][cw] + g0 >= L[r][g + 4][cw] + g1) ? 1.f : 0.f;
        }
        dec[r][g][cw] = d;
    }
    __syncthreads();

    unsigned int local_m = 0;
    if (t < GG * MW)
        local_m = (unsigned int)dec[1][t / MW][t - (t / MW) * MW];

    if (t < MW) {
        float a0 = fmaxf(fmaxf(dec[0][0][t], dec[0][1][t]), fmaxf(dec[0][2][t], dec[0][3][t]));
        float a1 = fmaxf(fmaxf(dec[1][0][t], dec[1][1][t]), fmaxf(dec[1][2][t], dec[1][3][t]));
        float a2 = fmaxf(fmaxf(dec[2][0][t], dec[2][1][t]), fmaxf(dec[2][2][t], dec[2][3][t]));
        R[0][t + 1] = fmaxf(a1, a0);
        R[1][t + 1] = a1;
        R[2][t + 1] = fmaxf(a1, a2);
    }
    if (t < 3) { R[t][0] = 0.f; R[t][MW + 1] = 0.f; }
    __syncthreads();

    // 1792 fine outputs: g(4) x hh(4) x w(112)
    unsigned int local_d = 0;
    #pragma unroll
    for (int k = 0; k < 7; ++k) {
        int idx = t + 256 * k;
        int g   = idx / 448;
        int rem = idx - g * 448;
        int hh  = rem / 112;
        int wfi = rem - hh * 112;
        int cw  = wfi >> 2;
        int wm  = wfi & 3;
        int rv  = (hh == 0) ? 0 : (hh == 3 ? 2 : 1);
        float d;
        if (wm == 0)      d = fmaxf(R[rv][cw],     R[rv][cw + 1]);
        else if (wm == 3) d = fmaxf(R[rv][cw + 1], R[rv][cw + 2]);
        else              d = R[rv][cw + 1];
        float mv = dec[1][g][cw];
        size_t o = (((size_t)b * GG + g) * 112 + (4 * ch + hh)) * 112 + wfi;
        out_mask[o] = mv;
        out_dil[o]  = d;
        local_d += (d > 0.5f) ? 1u : 0u;
    }

    // dual wave reduction
    #pragma unroll
    for (int off = 32; off; off >>= 1) {
        local_m += __shfl_down(local_m, off);
        local_d += __shfl_down(local_d, off);
    }
    if ((t & 63) == 0) { sm[t >> 6] = local_m; sd[t >> 6] = local_d; }
    __syncthreads();

    if (t == 0) {
        unsigned int bm = sm[0] + sm[1] + sm[2] + sm[3];
        unsigned int bd = sd[0] + sd[1] + sd[2] + sd[3];
        atomicAdd(&cnts[0], bm);
        atomicAdd(&cnts[1], bd);
        __threadfence();
        unsigned int prev = atomicAdd(&cnts[2], 1u);
        if (prev == NB * MH - 1) {          // last block: all counts visible
            unsigned int tm = atomicAdd(&cnts[0], 0u);
            unsigned int td = atomicAdd(&cnts[1], 0u);
            out_scalars[0] = (float)tm / 100352.0f;    // B*G*28*28
            out_scalars[1] = (float)td / 1605632.0f;   // B*G*112*112
            out_scalars[2] = 501760.0f;                // flops constant
        }
    }
}

extern "C" void kernel_launch(void* const* d_in, const int* in_sizes, int n_in,
                              void* d_out, int out_size, void* d_ws, size_t ws_size,
                              hipStream_t stream) {
    const float* x    = (const float*)d_in[0];
    const float* w    = (const float*)d_in[1];
    const float* bias = (const float*)d_in[2];
    const float* gum  = (const float*)d_in[3];

    float* out = (float*)d_out;
    const size_t n_mask = (size_t)NB * GG * 112 * 112;   // 1,605,632

    unsigned int* cnts = (unsigned int*)d_ws;
    float*        plog = (float*)((char*)d_ws + 256);    // 896*4*224*4B = 3.21 MB

    masker_pool<<<dim3(NB * MH * CSPLIT), 256, 0, stream>>>(x, w, plog, cnts);
    masker_fuse<<<dim3(NB * MH), 256, 0, stream>>>(plog, bias, gum,
                                                   out, out + n_mask,
                                                   cnts, out + 2 * n_mask);
}